// Round 1
// baseline (690.945 us; speedup 1.0000x reference)
//
#include <hip/hip_runtime.h>
#include <math.h>

#define NSV 8192
#define MSV 8192
#define CF 96
#define NCLS 20

// ---- workspace layout (float offsets) ----
#define WS_DIFF   0
#define WS_ALX    16
#define WS_ALY    (WS_ALX + MSV)
#define WS_ALZ    (WS_ALY + MSV)
#define WS_W1     (WS_ALZ + MSV)
#define WS_W2     (WS_W1 + NSV)
#define WS_B      (WS_W2 + MSV)
#define WS_A      (WS_B + NSV)
#define WS_CONF   (WS_A + MSV)
#define WS_PROW   (WS_CONF + MSV)          // N*32 partial row sums
#define WS_PCOL   (WS_PROW + NSV*32)       // M*32 partial col sums
#define WS_SMENC  (WS_PCOL + MSV*32)       // u64[M] packed argmax
#define WS_SMIDX  (WS_SMENC + 2*MSV)       // int[M]
#define WS_WIN    (WS_SMIDX + MSV)         // int[N]
#define WS_FLAG   (WS_WIN + NSV)           // int[1]
// total ~622,609 floats ~= 2.49 MB

// ---- output layout (floats) ----
#define O_TRUST 0
#define O_PROB  NSV
#define O_PRE   (O_PROB + NSV*NCLS)
#define O_SM    (O_PRE + NSV)

// 4x4 inverse (Gauss-Jordan, partial pivoting, fp64) then diff = inv(P1) @ P0
__global__ void k_inv(const float* __restrict__ posses, float* __restrict__ ws) {
  if (threadIdx.x != 0 || blockIdx.x != 0) return;
  double m[4][8];
  for (int r = 0; r < 4; ++r)
    for (int c = 0; c < 4; ++c) { m[r][c] = (double)posses[16 + r*4 + c]; m[r][4+c] = (r == c) ? 1.0 : 0.0; }
  for (int col = 0; col < 4; ++col) {
    int piv = col; double best = fabs(m[col][col]);
    for (int r = col+1; r < 4; ++r) { double v = fabs(m[r][col]); if (v > best) { best = v; piv = r; } }
    if (piv != col) for (int c = 0; c < 8; ++c) { double t = m[col][c]; m[col][c] = m[piv][c]; m[piv][c] = t; }
    double pv = m[col][col];
    for (int c = 0; c < 8; ++c) m[col][c] /= pv;
    for (int r = 0; r < 4; ++r) if (r != col) {
      double f = m[r][col];
      for (int c = 0; c < 8; ++c) m[r][c] -= f * m[col][c];
    }
  }
  for (int r = 0; r < 4; ++r)
    for (int c = 0; c < 4; ++c) {
      double s = 0.0;
      for (int k = 0; k < 4; ++k) s += m[r][4+k] * (double)posses[k*4 + c];
      ws[WS_DIFF + r*4 + c] = (float)s;
    }
}

// al_sur (transformed coords), row norms w1 (mean_features), w2 (sur_sv_feature)
__global__ void k_prep(const float* __restrict__ surf, const float* __restrict__ surc,
                       const float* __restrict__ meanf, float* __restrict__ ws) {
  int j = blockIdx.x * blockDim.x + threadIdx.x;
  if (j >= MSV) return;
  float d[12];
  #pragma unroll
  for (int q = 0; q < 12; ++q) d[q] = ws[WS_DIFF + q];
  float x = surc[j*3+0], y = surc[j*3+1], z = surc[j*3+2];
  ws[WS_ALX + j] = ((x*d[0] + y*d[1]) + z*d[2]) + d[3];
  ws[WS_ALY + j] = ((x*d[4] + y*d[5]) + z*d[6]) + d[7];
  ws[WS_ALZ + j] = ((x*d[8] + y*d[9]) + z*d[10]) + d[11];
  float s2 = 0.f, s1 = 0.f;
  for (int k = 0; k < CF; ++k) { float v = surf[(size_t)j*CF + k]; s2 += v*v; }
  for (int k = 0; k < CF; ++k) { float v = meanf[(size_t)j*CF + k]; s1 += v*v; }
  ws[WS_W2 + j] = sqrtf(s2);
  ws[WS_W1 + j] = sqrtf(s1);
}

// Heavy kernels: each block evaluates a 256x256 region of K.
// PASS 1: deterministic chunked row/col sums.  PASS 2: per-column argmax of (a*K)*b.
#define LDA 132

template <int PASS>
__global__ __launch_bounds__(256)
void k_pass(const float* __restrict__ meanf, const float* __restrict__ surf,
            const float* __restrict__ ori, float* __restrict__ ws) {
  __shared__ float As[32*LDA];
  __shared__ float Bs[32*LDA];
  __shared__ float w1s[256], orx[256], ory[256], orz[256];
  __shared__ float w2s[256], sax[256], say[256], saz[256];
  __shared__ float extra[(PASS == 1) ? 2688 : 5376];

  float* rowacc = extra;               // PASS1
  float* colacc = extra + 256;         // PASS1
  float* cred   = extra + 512;         // PASS1: 128*17
  float* bs_s   = extra;               // PASS2
  float* as_s   = extra + 256;         // PASS2
  float* bestv  = extra + 512;         // PASS2: 256
  int*   besti  = (int*)(extra + 768); // PASS2: 256
  float* vred   = extra + 1024;        // PASS2: 128*17
  int*   ired   = (int*)(extra + 1024 + 2176); // PASS2: 128*17

  int t = threadIdx.x;
  int ty = t >> 4, tx = t & 15;
  int bi = blockIdx.x, bj = blockIdx.y;
  int I0 = bi * 256, J0 = bj * 256;

  {
    int i = I0 + t, j = J0 + t;
    w1s[t] = ws[WS_W1 + i];
    orx[t] = ori[(size_t)i*3+0]; ory[t] = ori[(size_t)i*3+1]; orz[t] = ori[(size_t)i*3+2];
    w2s[t] = ws[WS_W2 + j];
    sax[t] = ws[WS_ALX + j]; say[t] = ws[WS_ALY + j]; saz[t] = ws[WS_ALZ + j];
    if (PASS == 1) { rowacc[t] = 0.f; colacc[t] = 0.f; }
    else { bs_s[t] = ws[WS_B + i]; as_s[t] = ws[WS_A + j]; }
  }
  __syncthreads();

  for (int jsub = 0; jsub < 2; ++jsub) {
    for (int isub = 0; isub < 2; ++isub) {
      float acc[8][8];
      #pragma unroll
      for (int u = 0; u < 8; ++u)
        #pragma unroll
        for (int v = 0; v < 8; ++v) acc[u][v] = 0.f;

      for (int kc = 0; kc < 3; ++kc) {
        __syncthreads();
        #pragma unroll
        for (int it = 0; it < 4; ++it) {
          int idx = it*256 + t;
          int row = idx >> 3;
          int kp  = idx & 7;
          const float4 av = *(const float4*)&meanf[(size_t)(I0 + isub*128 + row)*CF + kc*32 + kp*4];
          const float4 bv = *(const float4*)&surf [(size_t)(J0 + jsub*128 + row)*CF + kc*32 + kp*4];
          int k0 = kp*4;
          As[(k0+0)*LDA + row] = av.x; As[(k0+1)*LDA + row] = av.y;
          As[(k0+2)*LDA + row] = av.z; As[(k0+3)*LDA + row] = av.w;
          Bs[(k0+0)*LDA + row] = bv.x; Bs[(k0+1)*LDA + row] = bv.y;
          Bs[(k0+2)*LDA + row] = bv.z; Bs[(k0+3)*LDA + row] = bv.w;
        }
        __syncthreads();
        #pragma unroll
        for (int k = 0; k < 32; ++k) {
          const float4 a0 = *(const float4*)&As[k*LDA + ty*4];
          const float4 a1 = *(const float4*)&As[k*LDA + 64 + ty*4];
          const float4 b0 = *(const float4*)&Bs[k*LDA + tx*4];
          const float4 b1 = *(const float4*)&Bs[k*LDA + 64 + tx*4];
          float a[8] = {a0.x,a0.y,a0.z,a0.w,a1.x,a1.y,a1.z,a1.w};
          float b[8] = {b0.x,b0.y,b0.z,b0.w,b1.x,b1.y,b1.z,b1.w};
          #pragma unroll
          for (int u = 0; u < 8; ++u)
            #pragma unroll
            for (int v = 0; v < 8; ++v)
              acc[u][v] = fmaf(a[u], b[v], acc[u][v]);
        }
      }

      // epilogue: transform dot -> K, then reduce
      float colp[8];
      float tbv[8]; int tbi_[8];
      if (PASS == 1) {
        #pragma unroll
        for (int cc = 0; cc < 8; ++cc) colp[cc] = 0.f;
      }
      #pragma unroll
      for (int rr = 0; rr < 8; ++rr) {
        int rloc = isub*128 + ((rr < 4) ? (ty*4 + rr) : (64 + ty*4 + rr - 4));
        float w1v = w1s[rloc], ox = orx[rloc], oy = ory[rloc], oz = orz[rloc];
        float bvv = (PASS == 2) ? bs_s[rloc] : 0.f;
        float rowp = 0.f;
        #pragma unroll
        for (int cc = 0; cc < 8; ++cc) {
          int cloc = jsub*128 + ((cc < 4) ? (tx*4 + cc) : (64 + tx*4 + cc - 4));
          float den = fmaxf(w1v * w2s[cloc], 1e-8f);
          float fd = 1.0f - acc[rr][cc] / den;
          float dx = ox - sax[cloc], dy = oy - say[cloc], dz = oz - saz[cloc];
          float cd = (dx*dx + dy*dy + dz*dz) * 4.0f;
          float ev = expf(-0.5f * cd);
          float dm = 1.0f + fd - ev;
          float kv = expf(-dm / 0.03f);
          kv = (cd < 100.0f) ? kv : 0.0f;
          if (PASS == 1) {
            rowp += kv;
            colp[cc] += kv;
          } else {
            float val = (as_s[cloc] * kv) * bvv;   // matches (a[j]*K[i,j])*b[i]
            int grow = I0 + rloc;
            if (rr == 0) { tbv[cc] = val; tbi_[cc] = grow; }
            else if (val > tbv[cc]) { tbv[cc] = val; tbi_[cc] = grow; }
          }
        }
        if (PASS == 1) {
          rowp += __shfl_xor(rowp, 1);
          rowp += __shfl_xor(rowp, 2);
          rowp += __shfl_xor(rowp, 4);
          rowp += __shfl_xor(rowp, 8);
          if (tx == 0) rowacc[rloc] += rowp;
        }
      }
      if (PASS == 1) {
        #pragma unroll
        for (int cc = 0; cc < 8; ++cc) {
          int clo = (cc < 4) ? (tx*4 + cc) : (64 + tx*4 + cc - 4);
          cred[clo*17 + ty] = colp[cc];
        }
        __syncthreads();
        if (t < 128) {
          float s = 0.f;
          #pragma unroll
          for (int q = 0; q < 16; ++q) s += cred[t*17 + q];
          colacc[jsub*128 + t] += s;
        }
      } else {
        #pragma unroll
        for (int cc = 0; cc < 8; ++cc) {
          int clo = (cc < 4) ? (tx*4 + cc) : (64 + tx*4 + cc - 4);
          vred[clo*17 + ty] = tbv[cc];
          ired[clo*17 + ty] = tbi_[cc];
        }
        __syncthreads();
        if (t < 128) {
          float bvx = vred[t*17]; int bix = ired[t*17];
          #pragma unroll
          for (int q = 1; q < 16; ++q) {
            float v = vred[t*17 + q];
            if (v > bvx) { bvx = v; bix = ired[t*17 + q]; }
          }
          int c = jsub*128 + t;
          if (isub == 0 || bvx > bestv[c]) { bestv[c] = bvx; besti[c] = bix; }
        }
      }
      __syncthreads();
    }
  }

  if (PASS == 1) {
    ws[WS_PROW + (size_t)(I0 + t)*32 + bj] = rowacc[t];
    ws[WS_PCOL + (size_t)(J0 + t)*32 + bi] = colacc[t];
  } else {
    unsigned vb = __float_as_uint(bestv[t]);  // vals >= 0 -> bits monotone
    unsigned long long enc = ((unsigned long long)vb << 32)
                           | (unsigned long long)(0xFFFFFFFFu - (unsigned)besti[t]);
    atomicMax((unsigned long long*)(ws + WS_SMENC) + (J0 + t), enc);
  }
}

// reduce partials -> b, a; init winner/flag/smenc
__global__ void k_bvec(float* __restrict__ ws) {
  int i = blockIdx.x * blockDim.x + threadIdx.x;
  if (i < NSV) {
    const float* pr = ws + WS_PROW + (size_t)i*32;
    float s = 0.f;
    #pragma unroll
    for (int q = 0; q < 32; ++q) s += pr[q];
    ws[WS_B + i] = 0x1p-13f / (s * 0x1p-13f + 1e-16f);
    ((int*)(ws + WS_WIN))[i] = -1;
    if (i == 0) *((int*)(ws + WS_FLAG)) = 0;
  } else if (i < NSV + MSV) {
    int j = i - NSV;
    const float* pc = ws + WS_PCOL + (size_t)j*32;
    float s = 0.f;
    #pragma unroll
    for (int q = 0; q < 32; ++q) s += pc[q];
    ws[WS_A + j] = 0x1p-13f / (s * 0x1p-13f + 1e-16f);
    ((unsigned long long*)(ws + WS_SMENC))[j] = 0ull;
  }
}

__global__ void k_softmax(const float* __restrict__ svp, float* __restrict__ out) {
  int i = blockIdx.x * blockDim.x + threadIdx.x;
  if (i >= NSV) return;
  const float* x = svp + (size_t)i*NCLS;
  float mx = x[0];
  for (int c = 1; c < NCLS; ++c) mx = fmaxf(mx, x[c]);
  float e[NCLS]; float s = 0.f;
  for (int c = 0; c < NCLS; ++c) { e[c] = expf(x[c] - mx); s += e[c]; }
  float* p = out + O_PROB + (size_t)i*NCLS;
  for (int c = 0; c < NCLS; ++c) p[c] = e[c]/s;
}

__global__ void k_conf(const int* __restrict__ gt, float* __restrict__ ws, float* __restrict__ out) {
  int j = blockIdx.x * blockDim.x + threadIdx.x;
  if (j >= MSV) return;
  unsigned long long enc = ((const unsigned long long*)(ws + WS_SMENC))[j];
  int sm = (int)(0xFFFFFFFFu - (unsigned)(enc & 0xFFFFFFFFull));
  ((int*)(ws + WS_SMIDX))[j] = sm;
  out[O_SM + j] = (float)sm;
  float c = out[O_PROB + (size_t)sm*NCLS + gt[j]];
  ws[WS_CONF + j] = c;
  unsigned long long m = __ballot(c > 0.1f);
  if ((threadIdx.x & 63) == 0 && m) atomicOr((int*)(ws + WS_FLAG), 1);
}

__global__ void k_winner(float* __restrict__ ws) {
  int j = blockIdx.x * blockDim.x + threadIdx.x;
  if (j >= MSV) return;
  float c = ws[WS_CONF + j];
  int f = *((const int*)(ws + WS_FLAG));
  bool tm = f ? (c > 0.1f) : (c > 0.0f);
  if (tm) atomicMax(((int*)(ws + WS_WIN)) + ((const int*)(ws + WS_SMIDX))[j], j);  // last-write-wins == max j
}

__global__ void k_final(const int* __restrict__ gt, float* __restrict__ out, const float* __restrict__ ws) {
  int i = blockIdx.x * blockDim.x + threadIdx.x;
  if (i >= NSV) return;
  int w = ((const int*)(ws + WS_WIN))[i];
  float* row = out + O_PROB + (size_t)i*NCLS;
  if (w >= 0) {
    int g = gt[w];
    for (int c = 0; c < NCLS; ++c) row[c] = (c == g) ? 1.f : 0.f;
  }
  out[O_TRUST + i] = (w >= 0) ? 1.f : 0.f;
  float mx = row[0]; int pi = 0;
  for (int c = 1; c < NCLS; ++c) { float v = row[c]; if (v > mx) { mx = v; pi = c; } }
  out[O_PRE + i] = (float)pi;
}

extern "C" void kernel_launch(void* const* d_in, const int* in_sizes, int n_in,
                              void* d_out, int out_size, void* d_ws, size_t ws_size,
                              hipStream_t stream) {
  const float* surf  = (const float*)d_in[0];  // sur_sv_feature (M,96)
  const float* surc  = (const float*)d_in[1];  // sur_sv_coords  (M,3)
  const int*   gt    = (const int*)d_in[2];    // sur_sv_gt      (M,)
  const float* svp   = (const float*)d_in[3];  // sv_prob        (N,20)
  const float* meanf = (const float*)d_in[4];  // mean_features  (N,96)
  const float* ori   = (const float*)d_in[5];  // ori_coords     (N,3)
  const float* poss  = (const float*)d_in[6];  // posses         (2,4,4)
  float* out = (float*)d_out;
  float* ws  = (float*)d_ws;

  k_inv<<<1, 64, 0, stream>>>(poss, ws);
  k_prep<<<MSV/256, 256, 0, stream>>>(surf, surc, meanf, ws);
  k_pass<1><<<dim3(32, 32), 256, 0, stream>>>(meanf, surf, ori, ws);
  k_bvec<<<(NSV + MSV)/256, 256, 0, stream>>>(ws);
  k_pass<2><<<dim3(32, 32), 256, 0, stream>>>(meanf, surf, ori, ws);
  k_softmax<<<NSV/256, 256, 0, stream>>>(svp, out);
  k_conf<<<MSV/256, 256, 0, stream>>>(gt, ws, out);
  k_winner<<<MSV/256, 256, 0, stream>>>(ws);
  k_final<<<NSV/256, 256, 0, stream>>>(gt, out, ws);
}

// Round 2
// 496.762 us; speedup vs baseline: 1.3909x; 1.3909x over previous
//
#include <hip/hip_runtime.h>
#include <math.h>

typedef __attribute__((ext_vector_type(8))) short short8;
typedef __attribute__((ext_vector_type(16))) float floatx16;

#define NSV 8192
#define MSV 8192
#define CF 96
#define NCLS 20

// ---- workspace byte offsets ----
#define OFF_A0    0u
#define OFF_A1    1572864u
#define OFF_A2    3145728u
#define OFF_B0    4718592u
#define OFF_B1    6291456u
#define OFF_B2    7864320u
#define OFF_RV4   9437184u
#define OFF_CV4   9568256u
#define OFF_VB    9699328u
#define OFF_VA    9732096u
#define OFF_PROW  9764864u
#define OFF_PCOL  11862016u
#define OFF_SMENC 13959168u
#define OFF_SMIDX 14024704u
#define OFF_WIN   14057472u
#define OFF_CONF  14090240u
#define OFF_FLAG  14123008u
#define OFF_DIFF  14123072u
// total ~13.5 MB

// ---- output float offsets ----
#define O_TRUST 0
#define O_PROB  NSV
#define O_PRE   (O_PROB + NSV*NCLS)
#define O_SM    (O_PRE + NSV)

__device__ __forceinline__ unsigned short bfr(float x) {
  unsigned u = __float_as_uint(x);
  return (unsigned short)((u + 0x7FFFu + ((u >> 16) & 1u)) >> 16);
}
__device__ __forceinline__ float bff(unsigned short h) {
  return __uint_as_float(((unsigned)h) << 16);
}

// 4x4 inverse (fp64 Gauss-Jordan) then diff = inv(P1) @ P0
__global__ void k_inv(const float* __restrict__ posses, char* __restrict__ wsb) {
  if (threadIdx.x != 0 || blockIdx.x != 0) return;
  float* D = (float*)(wsb + OFF_DIFF);
  double m[4][8];
  for (int r = 0; r < 4; ++r)
    for (int c = 0; c < 4; ++c) { m[r][c] = (double)posses[16 + r*4 + c]; m[r][4+c] = (r == c) ? 1.0 : 0.0; }
  for (int col = 0; col < 4; ++col) {
    int piv = col; double best = fabs(m[col][col]);
    for (int r = col+1; r < 4; ++r) { double v = fabs(m[r][col]); if (v > best) { best = v; piv = r; } }
    if (piv != col) for (int c = 0; c < 8; ++c) { double tt = m[col][c]; m[col][c] = m[piv][c]; m[piv][c] = tt; }
    double pv = m[col][col];
    for (int c = 0; c < 8; ++c) m[col][c] /= pv;
    for (int r = 0; r < 4; ++r) if (r != col) {
      double f = m[r][col];
      for (int c = 0; c < 8; ++c) m[r][c] -= f * m[col][c];
    }
  }
  for (int r = 0; r < 4; ++r)
    for (int c = 0; c < 4; ++c) {
      double s = 0.0;
      for (int k = 0; k < 4; ++k) s += m[r][4+k] * (double)posses[k*4 + c];
      D[r*4 + c] = (float)s;
    }
}

// bf16 3-way split of meanf -> A0/A1/A2 and surf -> B0/B1/B2
__global__ void k_split(const float* __restrict__ meanf, const float* __restrict__ surf,
                        char* __restrict__ wsb) {
  const int NT = NSV*CF/4;
  int idx = blockIdx.x*256 + threadIdx.x;
  if (idx >= 2*NT) return;
  int m = idx >= NT;
  int base4 = (idx - (m ? NT : 0)) * 4;
  const float* src = m ? surf : meanf;
  unsigned short* d0 = (unsigned short*)(wsb + (m ? OFF_B0 : OFF_A0));
  unsigned short* d1 = (unsigned short*)(wsb + (m ? OFF_B1 : OFF_A1));
  unsigned short* d2 = (unsigned short*)(wsb + (m ? OFF_B2 : OFF_A2));
  float4 v = *(const float4*)(src + base4);
  float xs[4] = {v.x, v.y, v.z, v.w};
  unsigned short h0[4], h1[4], h2[4];
  #pragma unroll
  for (int c = 0; c < 4; ++c) {
    float x = xs[c];
    unsigned short a0 = bfr(x);  float r1 = x - bff(a0);
    unsigned short a1 = bfr(r1); float r2 = r1 - bff(a1);
    unsigned short a2 = bfr(r2);
    h0[c] = a0; h1[c] = a1; h2[c] = a2;
  }
  *(ushort4*)(d0 + base4) = make_ushort4(h0[0], h0[1], h0[2], h0[3]);
  *(ushort4*)(d1 + base4) = make_ushort4(h1[0], h1[1], h1[2], h1[3]);
  *(ushort4*)(d2 + base4) = make_ushort4(h2[0], h2[1], h2[2], h2[3]);
}

// norms, coord transform, packed per-row/per-col structs
__global__ void k_prep(const float* __restrict__ surf, const float* __restrict__ surc,
                       const float* __restrict__ meanf, const float* __restrict__ ori,
                       char* __restrict__ wsb) {
  int j = blockIdx.x*256 + threadIdx.x;
  if (j >= NSV) return;
  const float* D = (const float*)(wsb + OFF_DIFF);
  float d[12];
  #pragma unroll
  for (int q = 0; q < 12; ++q) d[q] = D[q];
  float x = surc[j*3+0], y = surc[j*3+1], z = surc[j*3+2];
  float ax = ((x*d[0] + y*d[1]) + z*d[2]) + d[3];
  float ay = ((x*d[4] + y*d[5]) + z*d[6]) + d[7];
  float az = ((x*d[8] + y*d[9]) + z*d[10]) + d[11];
  const float4* f2 = (const float4*)(surf  + (size_t)j*CF);
  const float4* f1 = (const float4*)(meanf + (size_t)j*CF);
  float s2 = 0.f, s1 = 0.f;
  #pragma unroll
  for (int kq = 0; kq < 24; ++kq) {
    float4 v = f2[kq]; s2 += v.x*v.x; s2 += v.y*v.y; s2 += v.z*v.z; s2 += v.w*v.w;
  }
  #pragma unroll
  for (int kq = 0; kq < 24; ++kq) {
    float4 v = f1[kq]; s1 += v.x*v.x; s1 += v.y*v.y; s1 += v.z*v.z; s1 += v.w*v.w;
  }
  float4 cvv; cvv.x = 1.0f/sqrtf(s2); cvv.y = ax; cvv.z = ay; cvv.w = az;
  ((float4*)(wsb + OFF_CV4))[j] = cvv;
  float4 rvv; rvv.x = 1.0f/sqrtf(s1); rvv.y = ori[j*3+0]; rvv.z = ori[j*3+1]; rvv.w = ori[j*3+2];
  ((float4*)(wsb + OFF_RV4))[j] = rvv;
}

// Heavy pass: 128x128 tile per block, 4 waves (2x2), wave tile 64x64 via 2x2 mfma_32x32x16_bf16.
// PASS 1: deterministic row/col partial sums.  PASS 2: per-column argmax of (a*K)*b.
template<int PASS>
__global__ __launch_bounds__(256, 2)
void k_pass(char* __restrict__ wsb) {
  const unsigned short* Asp[3] = {(const unsigned short*)(wsb+OFF_A0),
                                  (const unsigned short*)(wsb+OFF_A1),
                                  (const unsigned short*)(wsb+OFF_A2)};
  const unsigned short* Bsp[3] = {(const unsigned short*)(wsb+OFF_B0),
                                  (const unsigned short*)(wsb+OFF_B1),
                                  (const unsigned short*)(wsb+OFF_B2)};
  const float4* RV  = (const float4*)(wsb + OFF_RV4);
  const float4* CVC = (const float4*)(wsb + OFF_CV4);
  const float* VB = (const float*)(wsb + OFF_VB);
  const float* VA = (const float*)(wsb + OFF_VA);
  float* PROW = (float*)(wsb + OFF_PROW);
  float* PCOL = (float*)(wsb + OFF_PCOL);
  unsigned long long* SME = (unsigned long long*)(wsb + OFF_SMENC);

  __shared__ float rowred[2][128];
  __shared__ float colred[2][128];
  __shared__ unsigned long long encred[2][128];

  int t = threadIdx.x, lane = t & 63, wid = t >> 6;
  int wr = wid >> 1, wc = wid & 1, l31 = lane & 31, hi = lane >> 5;
  // XCD-aware swizzle: each XCD gets 8 contiguous bj columns -> B panel L2-resident
  int flat = blockIdx.y*64 + blockIdx.x;
  int xcd = flat & 7, q = flat >> 3;
  int bj = (xcd << 3) + (q >> 6), bi = q & 63;
  int I0 = bi*128, J0 = bj*128;

  int offA[2], offB[2];
  #pragma unroll
  for (int ti = 0; ti < 2; ++ti) {
    offA[ti] = (I0 + wr*64 + ti*32 + l31)*CF + hi*8;
    offB[ti] = (J0 + wc*64 + ti*32 + l31)*CF + hi*8;
  }

  floatx16 acc[2][2];
  #pragma unroll
  for (int ti = 0; ti < 2; ++ti)
    #pragma unroll
    for (int tj = 0; tj < 2; ++tj)
      #pragma unroll
      for (int e = 0; e < 16; ++e) acc[ti][tj][e] = 0.f;

  short8 fa[3][2], fb[3][2];
  #pragma unroll
  for (int s = 0; s < 3; ++s)
    #pragma unroll
    for (int ti = 0; ti < 2; ++ti) {
      fa[s][ti] = *(const short8*)(Asp[s] + offA[ti]);
      fb[s][ti] = *(const short8*)(Bsp[s] + offB[ti]);
    }

  #pragma unroll
  for (int ks = 0; ks < 6; ++ks) {
    short8 na[3][2], nb[3][2];
    if (ks < 5) {
      #pragma unroll
      for (int s = 0; s < 3; ++s)
        #pragma unroll
        for (int ti = 0; ti < 2; ++ti) {
          na[s][ti] = *(const short8*)(Asp[s] + offA[ti] + (ks+1)*16);
          nb[s][ti] = *(const short8*)(Bsp[s] + offB[ti] + (ks+1)*16);
        }
    }
    #pragma unroll
    for (int ti = 0; ti < 2; ++ti)
      #pragma unroll
      for (int tj = 0; tj < 2; ++tj) {
        acc[ti][tj] = __builtin_amdgcn_mfma_f32_32x32x16_bf16(fa[0][ti], fb[0][tj], acc[ti][tj], 0, 0, 0);
        acc[ti][tj] = __builtin_amdgcn_mfma_f32_32x32x16_bf16(fa[0][ti], fb[1][tj], acc[ti][tj], 0, 0, 0);
        acc[ti][tj] = __builtin_amdgcn_mfma_f32_32x32x16_bf16(fa[1][ti], fb[0][tj], acc[ti][tj], 0, 0, 0);
        acc[ti][tj] = __builtin_amdgcn_mfma_f32_32x32x16_bf16(fa[1][ti], fb[1][tj], acc[ti][tj], 0, 0, 0);
        acc[ti][tj] = __builtin_amdgcn_mfma_f32_32x32x16_bf16(fa[0][ti], fb[2][tj], acc[ti][tj], 0, 0, 0);
        acc[ti][tj] = __builtin_amdgcn_mfma_f32_32x32x16_bf16(fa[2][ti], fb[0][tj], acc[ti][tj], 0, 0, 0);
      }
    if (ks < 5) {
      #pragma unroll
      for (int s = 0; s < 3; ++s)
        #pragma unroll
        for (int ti = 0; ti < 2; ++ti) { fa[s][ti] = na[s][ti]; fb[s][ti] = nb[s][ti]; }
    }
  }

  // ---- epilogue ----
  float4 cv[2]; float avj[2];
  #pragma unroll
  for (int tj = 0; tj < 2; ++tj) {
    int j = J0 + wc*64 + tj*32 + l31;
    cv[tj] = CVC[j];
    avj[tj] = (PASS == 2) ? VA[j] : 0.f;
  }
  float colacc[2] = {0.f, 0.f};
  unsigned long long benc[2] = {0ull, 0ull};

  #pragma unroll
  for (int ti = 0; ti < 2; ++ti) {
    #pragma unroll
    for (int r = 0; r < 16; ++r) {
      int lr = wr*64 + ti*32 + (r & 3) + 8*(r >> 2) + 4*hi;
      int row = I0 + lr;
      float4 rv = RV[row];
      float bvv = (PASS == 2) ? VB[row] : 0.f;
      float rowp = 0.f;
      #pragma unroll
      for (int tj = 0; tj < 2; ++tj) {
        float dotv = acc[ti][tj][r];
        float cosv = dotv * rv.x * cv[tj].x;
        float dx = rv.y - cv[tj].y;
        float dy = rv.z - cv[tj].z;
        float dz = rv.w - cv[tj].w;
        float s3 = fmaf(dz, dz, fmaf(dy, dy, dx*dx));
        float ev = exp2f(s3 * -2.885390081777927f);       // exp(-2*s3)
        float arg = (cosv + ev - 2.0f) * 48.08983469629878f; // -dm/0.03 in log2
        float kv = exp2f(arg);
        kv = (s3 < 25.0f) ? kv : 0.0f;                     // support: cd<100
        if (PASS == 1) { colacc[tj] += kv; rowp += kv; }
        else {
          float val = (avj[tj]*kv)*bvv;
          unsigned long long e = ((unsigned long long)__float_as_uint(val) << 32)
                               | (unsigned long long)(0xFFFFFFFFu - (unsigned)row);
          benc[tj] = (e > benc[tj]) ? e : benc[tj];
        }
      }
      if (PASS == 1) {
        rowp += __shfl_xor(rowp, 1);
        rowp += __shfl_xor(rowp, 2);
        rowp += __shfl_xor(rowp, 4);
        rowp += __shfl_xor(rowp, 8);
        rowp += __shfl_xor(rowp, 16);
        if (l31 == 0) rowred[wc][lr] = rowp;
      }
    }
  }
  if (PASS == 1) {
    #pragma unroll
    for (int tj = 0; tj < 2; ++tj) {
      colacc[tj] += __shfl_xor(colacc[tj], 32);
      if (hi == 0) colred[wr][wc*64 + tj*32 + l31] = colacc[tj];
    }
  } else {
    #pragma unroll
    for (int tj = 0; tj < 2; ++tj) {
      unsigned long long o = __shfl_xor(benc[tj], 32);
      if (o > benc[tj]) benc[tj] = o;
      if (hi == 0) encred[wr][wc*64 + tj*32 + l31] = benc[tj];
    }
  }
  __syncthreads();
  if (t < 128) {
    if (PASS == 1) {
      PROW[(size_t)(I0 + t)*64 + bj] = rowred[0][t] + rowred[1][t];
      PCOL[(size_t)(J0 + t)*64 + bi] = colred[0][t] + colred[1][t];
    } else {
      unsigned long long e0 = encred[0][t], e1 = encred[1][t];
      atomicMax(SME + (J0 + t), e0 > e1 ? e0 : e1);
    }
  }
}

// reduce partials -> b, a; init winner/flag/smenc
__global__ void k_bvec(char* __restrict__ wsb) {
  int i = blockIdx.x*256 + threadIdx.x;
  if (i < NSV) {
    const float* p = (const float*)(wsb + OFF_PROW) + (size_t)i*64;
    float s = 0.f;
    #pragma unroll
    for (int q = 0; q < 64; ++q) s += p[q];
    ((float*)(wsb + OFF_VB))[i] = 0x1p-13f / (s * 0x1p-13f + 1e-16f);
    ((int*)(wsb + OFF_WIN))[i] = -1;
    if (i == 0) *((int*)(wsb + OFF_FLAG)) = 0;
  } else if (i < 2*NSV) {
    int j = i - NSV;
    const float* p = (const float*)(wsb + OFF_PCOL) + (size_t)j*64;
    float s = 0.f;
    #pragma unroll
    for (int q = 0; q < 64; ++q) s += p[q];
    ((float*)(wsb + OFF_VA))[j] = 0x1p-13f / (s * 0x1p-13f + 1e-16f);
    ((unsigned long long*)(wsb + OFF_SMENC))[j] = 0ull;
  }
}

__global__ void k_softmax(const float* __restrict__ svp, float* __restrict__ out) {
  int i = blockIdx.x*256 + threadIdx.x;
  if (i >= NSV) return;
  const float* x = svp + (size_t)i*NCLS;
  float mx = x[0];
  for (int c = 1; c < NCLS; ++c) mx = fmaxf(mx, x[c]);
  float e[NCLS]; float s = 0.f;
  for (int c = 0; c < NCLS; ++c) { e[c] = expf(x[c] - mx); s += e[c]; }
  float* p = out + O_PROB + (size_t)i*NCLS;
  for (int c = 0; c < NCLS; ++c) p[c] = e[c]/s;
}

__global__ void k_conf(const int* __restrict__ gt, char* __restrict__ wsb, float* __restrict__ out) {
  int j = blockIdx.x*256 + threadIdx.x;
  if (j >= MSV) return;
  unsigned long long enc = ((const unsigned long long*)(wsb + OFF_SMENC))[j];
  int sm = (int)(0xFFFFFFFFu - (unsigned)(enc & 0xFFFFFFFFull));
  ((int*)(wsb + OFF_SMIDX))[j] = sm;
  out[O_SM + j] = (float)sm;
  float c = out[O_PROB + (size_t)sm*NCLS + gt[j]];
  ((float*)(wsb + OFF_CONF))[j] = c;
  unsigned long long m = __ballot(c > 0.1f);
  if ((threadIdx.x & 63) == 0 && m) atomicOr((int*)(wsb + OFF_FLAG), 1);
}

__global__ void k_winner(char* __restrict__ wsb) {
  int j = blockIdx.x*256 + threadIdx.x;
  if (j >= MSV) return;
  float c = ((const float*)(wsb + OFF_CONF))[j];
  int f = *((const int*)(wsb + OFF_FLAG));
  bool tm = f ? (c > 0.1f) : (c > 0.0f);
  if (tm) atomicMax(((int*)(wsb + OFF_WIN)) + ((const int*)(wsb + OFF_SMIDX))[j], j);
}

__global__ void k_final(const int* __restrict__ gt, float* __restrict__ out, const char* __restrict__ wsb) {
  int i = blockIdx.x*256 + threadIdx.x;
  if (i >= NSV) return;
  int w = ((const int*)(wsb + OFF_WIN))[i];
  float* row = out + O_PROB + (size_t)i*NCLS;
  if (w >= 0) {
    int g = gt[w];
    for (int c = 0; c < NCLS; ++c) row[c] = (c == g) ? 1.f : 0.f;
  }
  out[O_TRUST + i] = (w >= 0) ? 1.f : 0.f;
  float mx = row[0]; int pi = 0;
  for (int c = 1; c < NCLS; ++c) { float v = row[c]; if (v > mx) { mx = v; pi = c; } }
  out[O_PRE + i] = (float)pi;
}

extern "C" void kernel_launch(void* const* d_in, const int* in_sizes, int n_in,
                              void* d_out, int out_size, void* d_ws, size_t ws_size,
                              hipStream_t stream) {
  const float* surf  = (const float*)d_in[0];
  const float* surc  = (const float*)d_in[1];
  const int*   gt    = (const int*)d_in[2];
  const float* svp   = (const float*)d_in[3];
  const float* meanf = (const float*)d_in[4];
  const float* ori   = (const float*)d_in[5];
  const float* poss  = (const float*)d_in[6];
  float* out = (float*)d_out;
  char* wsb = (char*)d_ws;

  k_inv<<<1, 64, 0, stream>>>(poss, wsb);
  k_split<<<1536, 256, 0, stream>>>(meanf, surf, wsb);
  k_prep<<<NSV/256, 256, 0, stream>>>(surf, surc, meanf, ori, wsb);
  k_pass<1><<<dim3(64, 64), 256, 0, stream>>>(wsb);
  k_bvec<<<2*NSV/256, 256, 0, stream>>>(wsb);
  k_pass<2><<<dim3(64, 64), 256, 0, stream>>>(wsb);
  k_softmax<<<NSV/256, 256, 0, stream>>>(svp, out);
  k_conf<<<MSV/256, 256, 0, stream>>>(gt, wsb, out);
  k_winner<<<MSV/256, 256, 0, stream>>>(wsb);
  k_final<<<NSV/256, 256, 0, stream>>>(gt, out, wsb);
}